// Round 6
// baseline (774.698 us; speedup 1.0000x reference)
//
#include <hip/hip_runtime.h>

typedef unsigned short u16;
typedef unsigned int u32;
typedef short short8 __attribute__((ext_vector_type(8)));
typedef float f32x4 __attribute__((ext_vector_type(4)));

#define HW 128

__device__ __forceinline__ float bf2f(u16 h) {
    u32 u = ((u32)h) << 16;
    return __uint_as_float(u);
}
__device__ __forceinline__ u16 f2bf(float f) {
    u32 u = __float_as_uint(f);
    u32 r = (u + 0x7FFFu + ((u >> 16) & 1u)) >> 16;
    return (u16)r;
}
__device__ __forceinline__ float lrelu_f(float v) {
    return v >= 0.f ? v : 0.1f * v;
}

// ---------------- halo ring clear for NHWC [16][Wd][Wd][C] bf16
template<int Wd, int C, int PAD>
__global__ __launch_bounds__(256) void clear_ring(u16* __restrict__ buf) {
    int row = blockIdx.x % Wd;
    int b = blockIdx.x / Wd;
    u32* rp = (u32*)(buf + ((size_t)b * Wd + row) * (Wd * C));
    if (row < PAD || row >= Wd - PAD) {
        for (int i = threadIdx.x; i < Wd * C / 2; i += 256) rp[i] = 0;
    } else {
        u32* rq = (u32*)((u16*)rp + (Wd - PAD) * C);
        for (int i = threadIdx.x; i < PAD * C / 2; i += 256) {
            rp[i] = 0;
            rq[i] = 0;
        }
    }
}

// ---------------- halo clear for feat2 fragment layout [16][134][12][144][8]
__global__ __launch_bounds__(256) void clear_feat2_halo(u16* __restrict__ f2) {
    int row = blockIdx.x % 134;
    int b = blockIdx.x / 134;
    u16* rp = f2 + ((size_t)b * 134 + row) * (12 * 144 * 8);
    if (row < 3 || row >= 131) {
        u32* p = (u32*)rp;
        for (int i = threadIdx.x; i < 12 * 144 * 4; i += 256) p[i] = 0;
    } else {
        for (int i = threadIdx.x; i < 12 * 16 * 4; i += 256) {
            int w = i & 3; int t = i >> 2;
            int xc = t & 15; int cg = t >> 4;
            int x = xc < 3 ? xc : 131 + (xc - 3);
            ((u32*)(rp + (cg * 144 + x) * 8))[w] = 0;
        }
    }
}

// ---------------- weight pack for MFMA convs: [oc][ic][3][3] f32 -> [tap][ch][quad][oc][j8] bf16
template<int ICR, int ICP, int OC>
__global__ __launch_bounds__(256) void pack_w(const float* __restrict__ w, u16* __restrict__ dst) {
    constexpr int NCH = ICP / 32;
    constexpr int NTOT = 9 * NCH * 4 * OC * 8;
    int gid = blockIdx.x * 256 + threadIdx.x;
    if (gid >= NTOT) return;
    int j = gid & 7;
    int t = gid >> 3;
    int oc = t % OC; t /= OC;
    int quad = t & 3; t >>= 2;
    int ch = t % NCH;
    int tap = t / NCH;
    int ic = ch * 32 + quad * 8 + j;
    int ky = tap / 3, kx = tap % 3;
    float v = (ic < ICR) ? w[((oc * ICR + ic) * 3 + ky) * 3 + kx] : 0.f;
    dst[gid] = f2bf(v);
}

// ---------------- conv4 weight pack: [2][32][5][5] f32 -> [tap(25)][oc(2)][ic(32)] f32
__global__ __launch_bounds__(256) void pack_w4(const float* __restrict__ w, float* __restrict__ dst) {
    int gid = blockIdx.x * 256 + threadIdx.x;
    if (gid >= 1600) return;
    int ic = gid & 31;
    int t = gid >> 5;
    int oc = t & 1;
    int tap = t >> 1;
    dst[(tap * 2 + oc) * 32 + ic] = w[(oc * 32 + ic) * 25 + tap];
}

// ---------------- upflow: transposed conv, lhs_dilation=2, pad=2, k=4, groups=2
__global__ __launch_bounds__(256) void upflow_kernel(const float* __restrict__ tflow, const float* __restrict__ wu,
                                                     float* __restrict__ flow) {
    int gid = blockIdx.x * 256 + threadIdx.x;   // 524288 exact
    int x = gid & 127;
    int y = (gid >> 7) & 127;
    int c = (gid >> 14) & 1;
    int b = gid >> 15;
    float acc = 0.f;
#pragma unroll
    for (int ky = 0; ky < 4; ++ky) {
        int u = y + ky - 2;
        if ((u & 1) || u < 0 || u > 126) continue;
        int iy = u >> 1;
#pragma unroll
        for (int kx = 0; kx < 4; ++kx) {
            int v = x + kx - 2;
            if ((v & 1) || v < 0 || v > 126) continue;
            int ix = v >> 1;
            acc += tflow[((b * 2 + c) * 64 + iy) * 64 + ix] *
                   wu[c * 16 + (3 - ky) * 4 + (3 - kx)];
        }
    }
    flow[gid] = acc;
}

// ---------------- backward warp -> fragment-native bf16 feat2 [b][row 134][cg 12][x 144][8]
__global__ __launch_bounds__(256) void warp_kernel(const float* __restrict__ second, const float* __restrict__ flow,
                                                   u16* __restrict__ feat2) {
    int tid = threadIdx.x;
    int x = tid & 127;
    int half = tid >> 7;            // 0..1
    int blk = blockIdx.x;           // (b*128 + y)*6 + cgp
    int cgp = blk % 6;
    int t = blk / 6;
    int y = t & 127;
    int b = t >> 7;
    int cg = cgp * 2 + half;        // 0..11

    float fx = (float)x + 2.5f * flow[((b * 2 + 0) * HW + y) * HW + x];
    float fy = (float)y + 2.5f * flow[((b * 2 + 1) * HW + y) * HW + x];
    float x0f = floorf(fx), y0f = floorf(fy);
    int x0 = (int)x0f, y0 = (int)y0f;
    int x1 = x0 + 1, y1 = y0 + 1;
    float wx1 = fx - x0f, wx0 = (x0f + 1.f) - fx;
    float wy1 = fy - y0f, wy0 = (y0f + 1.f) - fy;
    float wA = wx0 * wy0, wB = wx1 * wy0, wC = wx0 * wy1, wD = wx1 * wy1;
    float vA = (x0 >= 0 && x0 <= 127 && y0 >= 0 && y0 <= 127) ? 1.f : 0.f;
    float vB = (x1 >= 0 && x1 <= 127 && y0 >= 0 && y0 <= 127) ? 1.f : 0.f;
    float vC = (x0 >= 0 && x0 <= 127 && y1 >= 0 && y1 <= 127) ? 1.f : 0.f;
    float vD = (x1 >= 0 && x1 <= 127 && y1 >= 0 && y1 <= 127) ? 1.f : 0.f;
    wA *= vA; wB *= vB; wC *= vC; wD *= vD;
    float ones = wA + wB + wC + wD;
    float maskf = (ones > 0.999f) ? 1.f : 0.f;
    wA *= maskf; wB *= maskf; wC *= maskf; wD *= maskf;
    int xc0 = min(max(x0, 0), 127), xc1 = min(max(x1, 0), 127);
    int yc0 = min(max(y0, 0), 127), yc1 = min(max(y1, 0), 127);
    int i00 = yc0 * HW + xc0, i01 = yc0 * HW + xc1;
    int i10 = yc1 * HW + xc0, i11 = yc1 * HW + xc1;

    const float* base = second + (size_t)b * 96 * HW * HW + (size_t)(cg * 8) * (HW * HW);
    short8 o;
#pragma unroll
    for (int j = 0; j < 8; ++j) {
        const float* pp = base + (size_t)j * (HW * HW);
        float v = wA * pp[i00] + wB * pp[i01] + wC * pp[i10] + wD * pp[i11];
        o[j] = (short)f2bf(v);
    }
    *(short8*)(feat2 + ((((size_t)(b * 134) + y + 3) * 12 + cg) * 144 + (x + 3)) * 8) = o;
}

// ---------------- correlation as banded MFMA GEMM -> NHWC (16,130,130,64) bf16 corr, + /96 + lrelu
// also zeroes pad channels 49..63 for its interior pixels
__global__ __launch_bounds__(256) void corr_mfma(const float* __restrict__ first, const u16* __restrict__ feat2,
                                                 u16* __restrict__ corrp) {
    int tid = threadIdx.x;
    int wave = tid >> 6, lane = tid & 63;
    int quad = lane >> 4, l16 = lane & 15;
    int blk = blockIdx.x;            // 16 * 128 * 2 = 4096
    int half = blk & 1;
    int y = (blk >> 1) & 127;
    int b = blk >> 8;
    int x0 = (half * 4 + wave) * 16;

    // A fragments: lane m=l16 -> pixel x0+l16, k = ch*32 + quad*8 + j
    short8 afr[3];
    const float* fbase = first + ((size_t)(b * 96) * HW + y) * HW + x0 + l16;
#pragma unroll
    for (int ch = 0; ch < 3; ++ch) {
        short8 a;
#pragma unroll
        for (int j = 0; j < 8; ++j)
            a[j] = (short)f2bf(fbase[(size_t)(ch * 32 + quad * 8 + j) * (HW * HW)]);
        afr[ch] = a;
    }

    f32x4 acc[7][2];
#pragma unroll
    for (int dy = 0; dy < 7; ++dy) {
        acc[dy][0] = (f32x4){0.f, 0.f, 0.f, 0.f};
        acc[dy][1] = (f32x4){0.f, 0.f, 0.f, 0.f};
    }

#pragma unroll
    for (int dy = 0; dy < 7; ++dy) {
#pragma unroll
        for (int ch = 0; ch < 3; ++ch) {
            const u16* rp = feat2 + ((((size_t)(b * 134) + y + dy) * 12 + ch * 4 + quad) * 144 + x0 + l16) * 8;
            short8 b0 = *(const short8*)(rp);
            short8 b1 = *(const short8*)(rp + 16 * 8);
            acc[dy][0] = __builtin_amdgcn_mfma_f32_16x16x32_bf16(afr[ch], b0, acc[dy][0], 0, 0, 0);
            acc[dy][1] = __builtin_amdgcn_mfma_f32_16x16x32_bf16(afr[ch], b1, acc[dy][1], 0, 0, 0);
        }
    }

    // band extract: dx = nt*16+l16-m
    u16* op = corrp + ((size_t)(b * 130) + y + 1) * (130 * 64);
#pragma unroll
    for (int dy = 0; dy < 7; ++dy)
#pragma unroll
        for (int nt = 0; nt < 2; ++nt)
#pragma unroll
            for (int r = 0; r < 4; ++r) {
                int m = quad * 4 + r;
                int dx = nt * 16 + l16 - m;
                if (dx >= 0 && dx < 7) {
                    float v = lrelu_f(acc[dy][nt][r] * (1.f / 96.f));
                    op[(size_t)(x0 + m + 1) * 64 + dy * 7 + dx] = f2bf(v);
                }
            }

    // zero pad channels 49..63 for this block's 64 interior pixels (cols half*64+1 .. half*64+64)
    {
        int pxl = tid >> 2;                     // 0..63
        int col = half * 64 + pxl + 1;
        int st = 49 + (tid & 3) * 4;
        int cnt = ((tid & 3) == 3) ? 3 : 4;
        u16* pz = op + (size_t)col * 64;
        for (int i = 0; i < cnt; ++i) pz[st + i] = 0;
    }
}

// ---------------- MFMA conv 3x3: NHWC pad-1 in (130x130xICP) -> NHWC pad-PADOUT out, + bias + lrelu
// wave tile: 64 px x OCB oc (OCB=32 -> acc[4][2], ~5 waves/SIMD)
template<int ICP, int OC, int OCB, int PADOUT>
__global__ __launch_bounds__(256) void conv_mfma(const u16* __restrict__ in, const u16* __restrict__ wp,
                                                 const float* __restrict__ bias, u16* __restrict__ out) {
    constexpr int NCH = ICP / 32;
    constexpr int NOCT = OCB / 16;
    constexpr int OCG = OC / OCB;
    constexpr int Wi = 130;
    constexpr int Wo = 128 + 2 * PADOUT;
    int tid = threadIdx.x;
    int wave = tid >> 6, lane = tid & 63;
    int quad = lane >> 4, l16 = lane & 15;
    int rowpair = blockIdx.x & 63;
    int t = blockIdx.x >> 6;
    int ocg = t % OCG;
    int b = t / OCG;
    int row = rowpair * 2 + (wave >> 1);
    int px0 = (wave & 1) * 64;
    int oc0 = ocg * OCB;

    float bv[NOCT];
#pragma unroll
    for (int ot = 0; ot < NOCT; ++ot) bv[ot] = bias[oc0 + ot * 16 + l16];

    f32x4 acc[4][NOCT];
#pragma unroll
    for (int mt = 0; mt < 4; ++mt)
#pragma unroll
        for (int ot = 0; ot < NOCT; ++ot)
            acc[mt][ot] = (f32x4){0.f, 0.f, 0.f, 0.f};

#pragma unroll
    for (int ky = 0; ky < 3; ++ky) {
#pragma unroll
        for (int kx = 0; kx < 3; ++kx) {
#pragma unroll
            for (int ch = 0; ch < NCH; ++ch) {
                const u16* aptr = in + ((size_t)(b * Wi + row + ky) * Wi + px0 + kx + l16) * ICP + ch * 32 + quad * 8;
                short8 afr[4];
#pragma unroll
                for (int mt = 0; mt < 4; ++mt)
                    afr[mt] = *(const short8*)(aptr + mt * 16 * ICP);
                const u16* bptr = wp + ((((size_t)(ky * 3 + kx) * NCH + ch) * 4 + quad) * OC + oc0 + l16) * 8;
                short8 bfr[NOCT];
#pragma unroll
                for (int ot = 0; ot < NOCT; ++ot)
                    bfr[ot] = *(const short8*)(bptr + ot * 16 * 8);
#pragma unroll
                for (int mt = 0; mt < 4; ++mt)
#pragma unroll
                    for (int ot = 0; ot < NOCT; ++ot)
                        acc[mt][ot] = __builtin_amdgcn_mfma_f32_16x16x32_bf16(afr[mt], bfr[ot], acc[mt][ot], 0, 0, 0);
            }
        }
    }

#pragma unroll
    for (int mt = 0; mt < 4; ++mt) {
#pragma unroll
        for (int ot = 0; ot < NOCT; ++ot) {
#pragma unroll
            for (int r = 0; r < 4; ++r) {
                int px = px0 + mt * 16 + quad * 4 + r;
                float v = lrelu_f(acc[mt][ot][r] + bv[ot]);
                out[((size_t)(b * Wo + row + PADOUT) * Wo + px + PADOUT) * OC + oc0 + ot * 16 + l16] = f2bf(v);
            }
        }
    }
}

// ---------------- conv4: 5x5, 32->2, NHWC pad-2 in (132x132x32), + flow add -> NCHW f32 out
__global__ __launch_bounds__(256) void conv4_kernel(const u16* __restrict__ in, const float* __restrict__ w4p,
                                                    const float* __restrict__ b4, const float* __restrict__ flow,
                                                    float* __restrict__ out) {
    int gid = blockIdx.x * 256 + threadIdx.x;   // 16*128*128
    int x = gid & 127;
    int y = (gid >> 7) & 127;
    int b = gid >> 14;
    float acc0 = b4[0], acc1 = b4[1];
#pragma unroll
    for (int ky = 0; ky < 5; ++ky) {
#pragma unroll
        for (int kx = 0; kx < 5; ++kx) {
            const u16* p = in + ((size_t)(b * 132 + y + ky) * 132 + x + kx) * 32;
            const float* wb = w4p + (ky * 5 + kx) * 64;
#pragma unroll
            for (int g = 0; g < 4; ++g) {
                short8 vv = *(const short8*)(p + g * 8);
#pragma unroll
                for (int j = 0; j < 8; ++j) {
                    float v = bf2f((u16)vv[j]);
                    acc0 += v * wb[g * 8 + j];
                    acc1 += v * wb[32 + g * 8 + j];
                }
            }
        }
    }
    int o0 = ((b * 2 + 0) * HW + y) * HW + x;
    int o1 = o0 + HW * HW;
    out[o0] = acc0 + flow[o0];
    out[o1] = acc1 + flow[o1];
}

// ---------------- launch
extern "C" void kernel_launch(void* const* d_in, const int* in_sizes, int n_in,
                              void* d_out, int out_size, void* d_ws, size_t ws_size,
                              hipStream_t stream) {
    const float* ffirst  = (const float*)d_in[2];
    const float* fsecond = (const float*)d_in[3];
    const float* tflow   = (const float*)d_in[4];
    const float* wu      = (const float*)d_in[5];
    const float* w1 = (const float*)d_in[6];
    const float* b1 = (const float*)d_in[7];
    const float* w2 = (const float*)d_in[8];
    const float* b2 = (const float*)d_in[9];
    const float* w3 = (const float*)d_in[10];
    const float* b3 = (const float*)d_in[11];
    const float* w4 = (const float*)d_in[12];
    const float* b4 = (const float*)d_in[13];
    float* out = (float*)d_out;
    char* ws = (char*)d_ws;

    // packed weights
    u16* w1p = (u16*)(ws + 0);         // 147456 B
    u16* w2p = (u16*)(ws + 147456);    // 147456 B
    u16* w3p = (u16*)(ws + 294912);    // 36864 B
    float* w4p = (float*)(ws + 331776);// 6400 B

    float* flow = (float*)(ws + 602112);   // 2097152 B, ends 2699264
    u16* regA = (u16*)(ws + 2699264);      // feat2 59.3MB -> x1p 69.2MB -> x3p 17.8MB
    u16* regB = (u16*)(ws + 71921664);     // corr 34.6MB -> x2p 34.6MB; end 106532864

    // 1) weight packing + upfront halo clears (no full memsets)
    pack_w<49, 64, 128><<<288, 256, 0, stream>>>(w1, w1p);
    pack_w<128, 128, 64><<<288, 256, 0, stream>>>(w2, w2p);
    pack_w<64, 64, 32><<<72, 256, 0, stream>>>(w3, w3p);
    pack_w4<<<7, 256, 0, stream>>>(w4, w4p);
    clear_feat2_halo<<<2144, 256, 0, stream>>>(regA);
    clear_ring<130, 64, 1><<<2080, 256, 0, stream>>>(regB);    // corr ring (inherited later by x2p)

    // 2) upflow -> flow (f32 NCHW)
    upflow_kernel<<<2048, 256, 0, stream>>>(tflow, wu, flow);

    // 3) warp -> feat2 fragment-native [16][134][12][144][8] bf16
    warp_kernel<<<12288, 256, 0, stream>>>(fsecond, flow, regA);

    // 4) correlation (banded MFMA) + lrelu + ch-pad zero -> corr NHWC (130,130,64) bf16
    corr_mfma<<<4096, 256, 0, stream>>>(ffirst, regA, regB);

    // 4b) x1p halo ring (after corr: regA feat2 dead region-wise for the ring)
    clear_ring<130, 128, 1><<<2080, 256, 0, stream>>>(regA);

    // 5) conv1 64->128 MFMA -> x1p NHWC pad1
    conv_mfma<64, 128, 32, 1><<<4096, 256, 0, stream>>>(regB, w1p, b1, regA);

    // 6) conv2 128->64 MFMA -> x2p NHWC pad1 (ring inherited zero from corr clear)
    conv_mfma<128, 64, 32, 1><<<2048, 256, 0, stream>>>(regA, w2p, b2, regB);

    // 6b) x3p halo ring (x1p dead)
    clear_ring<132, 32, 2><<<2112, 256, 0, stream>>>(regA);

    // 7) conv3 64->32 MFMA -> x3p NHWC pad2
    conv_mfma<64, 32, 32, 2><<<1024, 256, 0, stream>>>(regB, w3p, b3, regA);

    // 8) conv4 5x5 32->2 + flow add -> d_out (f32 NCHW)
    conv4_kernel<<<1024, 256, 0, stream>>>(regA, w4p, b4, flow, out);
}